// Round 1
// baseline (917.355 us; speedup 1.0000x reference)
//
#include <hip/hip_runtime.h>

#define Nn 10000
#define Ee 320000
#define CC 27
#define NEG 0.2f
#define TOT 270000      // Nn*CC
#define HIDn 450
#define FINALn 128
#define FC1_ROWS 264

// ---------------- CSR build ----------------
__global__ void k_deg(const int* __restrict__ ei, int* __restrict__ deg) {
    int e = blockIdx.x * blockDim.x + threadIdx.x;
    if (e < Ee) atomicAdd(&deg[ei[Ee + e]], 1);
}

__global__ __launch_bounds__(1024) void k_scan(const int* __restrict__ deg,
                                               int* __restrict__ off,
                                               int* __restrict__ cursor) {
    __shared__ int sums[1024];
    int tid = threadIdx.x;
    const int CH = 10;                       // 1024*10 >= Nn
    int start = tid * CH;
    int local[CH];
    int s = 0;
    #pragma unroll
    for (int i = 0; i < CH; ++i) {
        int idx = start + i;
        int v = (idx < Nn) ? deg[idx] : 0;
        local[i] = v; s += v;
    }
    sums[tid] = s;
    __syncthreads();
    for (int d = 1; d < 1024; d <<= 1) {
        int v = (tid >= d) ? sums[tid - d] : 0;
        __syncthreads();
        sums[tid] += v;
        __syncthreads();
    }
    int run = sums[tid] - s;                 // exclusive prefix
    #pragma unroll
    for (int i = 0; i < CH; ++i) {
        int idx = start + i;
        if (idx < Nn) { off[idx] = run; cursor[idx] = run; run += local[i]; }
    }
    if (tid == 1023) off[Nn] = sums[1023];
}

__global__ void k_scatter(const int* __restrict__ ei, int* __restrict__ cursor,
                          int* __restrict__ srcS, int* __restrict__ eidS) {
    int e = blockIdx.x * blockDim.x + threadIdx.x;
    if (e < Ee) {
        int d = ei[Ee + e];
        int p = atomicAdd(&cursor[d], 1);
        srcS[p] = ei[e];
        eidS[p] = e;
    }
}

// ---------------- NNConv messages: one lane = one edge ----------------
// msg[o] = sum_i x[s,i] * ( b2[i*64+o] + sum_k relu(ea@W1+b1)[k] * W2[k, i*64+o] )
// W2/W1/B1/B2 accessed with wave-uniform indices -> SMEM scalar operands.
__global__ __launch_bounds__(256) void k_msg(
    const float* __restrict__ x, const float* __restrict__ ea,
    const float* __restrict__ W1, const float* __restrict__ B1,
    const float* __restrict__ W2, const float* __restrict__ B2,
    const int* __restrict__ srcS, const int* __restrict__ eidS,
    float* __restrict__ msgbuf)
{
    int q = blockIdx.x * 256 + threadIdx.x;
    if (q >= Ee) return;
    int e = eidS[q];
    int s = srcS[q];
    float2 eav = *(const float2*)(ea + 2 * (size_t)e);
    float xs0 = x[s*5+0], xs1 = x[s*5+1], xs2 = x[s*5+2], xs3 = x[s*5+3], xs4 = x[s*5+4];

    float msg[64];
    #pragma unroll
    for (int o = 0; o < 64; ++o)
        msg[o] = xs0*B2[o] + xs1*B2[64+o] + xs2*B2[128+o] + xs3*B2[192+o] + xs4*B2[256+o];

    for (int k = 0; k < 32; ++k) {
        float hk = fmaxf(eav.x * W1[k] + eav.y * W1[32+k] + B1[k], 0.f);
        float t0 = hk*xs0, t1 = hk*xs1, t2 = hk*xs2, t3 = hk*xs3, t4 = hk*xs4;
        const float* __restrict__ w = W2 + k * 320;
        #pragma unroll
        for (int o = 0; o < 64; ++o)
            msg[o] += t0*w[o] + t1*w[64+o] + t2*w[128+o] + t3*w[192+o] + t4*w[256+o];
    }
    float4* mb = (float4*)(msgbuf + (size_t)q * 64);
    #pragma unroll
    for (int o4 = 0; o4 < 16; ++o4)
        mb[o4] = make_float4(msg[4*o4], msg[4*o4+1], msg[4*o4+2], msg[4*o4+3]);
}

// ---------------- aggregate + root + GAT projection (wave per node) ----------------
__global__ __launch_bounds__(256) void k_nodeagg(
    const float* __restrict__ msgbuf, const int* __restrict__ off,
    const float* __restrict__ x, const float* __restrict__ nnroot,
    const float* __restrict__ nnbias, const float* __restrict__ gw,
    const float* __restrict__ attsrc, const float* __restrict__ attdst,
    float* __restrict__ xl, float* __restrict__ asrcA, float* __restrict__ adstA)
{
    int wave = threadIdx.x >> 6;
    int lane = threadIdx.x & 63;
    int n = blockIdx.x * 4 + wave;
    if (n >= Nn) return;
    int beg = off[n], end = off[n + 1];

    float aggv = 0.f;
    for (int j = beg; j < end; ++j) aggv += msgbuf[(size_t)j * 64 + lane];

    float xn0 = x[n*5+0], xn1 = x[n*5+1], xn2 = x[n*5+2], xn3 = x[n*5+3], xn4 = x[n*5+4];
    float v = aggv + nnbias[lane]
            + xn0*nnroot[lane] + xn1*nnroot[64+lane] + xn2*nnroot[128+lane]
            + xn3*nnroot[192+lane] + xn4*nnroot[256+lane];
    float x1v = fmaxf(v, 0.f);

    int c = (lane < CC) ? lane : 0;
    float xlc = 0.f;
    #pragma unroll
    for (int o = 0; o < 64; ++o) {
        float xo = __shfl(x1v, o);
        xlc += xo * gw[o * CC + c];
    }
    float as_ = (lane < CC) ? xlc * attsrc[c] : 0.f;
    float ad_ = (lane < CC) ? xlc * attdst[c] : 0.f;
    #pragma unroll
    for (int d = 1; d < 64; d <<= 1) {
        as_ += __shfl_xor(as_, d);
        ad_ += __shfl_xor(ad_, d);
    }
    if (lane < CC) xl[n * CC + lane] = xlc;
    if (lane == 0) { asrcA[n] = as_; adstA[n] = ad_; }
}

// ---------------- GAT softmax-aggregate (wave per node, CSR + implicit self loop) ----
__global__ __launch_bounds__(256) void k_gat(
    const int* __restrict__ off, const int* __restrict__ srcS,
    const float* __restrict__ xl, const float* __restrict__ asrcA,
    const float* __restrict__ adstA, const float* __restrict__ gbias,
    float* __restrict__ x2f)
{
    int wave = threadIdx.x >> 6;
    int lane = threadIdx.x & 63;
    int n = blockIdx.x * 4 + wave;
    if (n >= Nn) return;
    int beg = off[n], end = off[n + 1];

    float adn = adstA[n];
    float aself = asrcA[n] + adn; aself = aself >= 0.f ? aself : NEG * aself;

    float m = aself;
    for (int j = beg + lane; j < end; j += 64) {
        float al = asrcA[srcS[j]] + adn; al = al >= 0.f ? al : NEG * al;
        m = fmaxf(m, al);
    }
    #pragma unroll
    for (int d = 1; d < 64; d <<= 1) m = fmaxf(m, __shfl_xor(m, d));

    int c = (lane < CC) ? lane : 0;
    float wself = __expf(aself - m);
    float denom = wself;
    float acc = wself * xl[n * CC + c];
    for (int j = beg; j < end; ++j) {
        int s = srcS[j];
        float al = asrcA[s] + adn; al = al >= 0.f ? al : NEG * al;
        float w = __expf(al - m);
        denom += w;
        acc += w * xl[s * CC + c];
    }
    if (lane < CC) {
        float r = acc / denom + gbias[c];
        x2f[n * CC + lane] = fmaxf(r, 0.f);
    }
}

// ---------------- fc1: 486MB matvec, skip zero rows ----------------
__global__ __launch_bounds__(512) void k_fc1(
    const float* __restrict__ x2f, const float* __restrict__ fw,
    float* __restrict__ v1acc)
{
    int j = threadIdx.x;
    int t0 = blockIdx.x * FC1_ROWS;
    int t1 = t0 + FC1_ROWS; if (t1 > TOT) t1 = TOT;
    if (j >= HIDn) return;
    float acc = 0.f;
    for (int t = t0; t < t1; t += 4) {
        float4 sv = *(const float4*)(x2f + t);   // broadcast scalar per wave
        if (sv.x != 0.f) acc += sv.x * fw[(size_t)t       * HIDn + j];
        if (sv.y != 0.f) acc += sv.y * fw[(size_t)(t + 1) * HIDn + j];
        if (sv.z != 0.f) acc += sv.z * fw[(size_t)(t + 2) * HIDn + j];
        if (sv.w != 0.f) acc += sv.w * fw[(size_t)(t + 3) * HIDn + j];
    }
    atomicAdd(&v1acc[j], acc);
}

// ---------------- fc2 + final relu (single block, split i-dim for ILP) -------------
__global__ __launch_bounds__(1024) void k_fc2(
    const float* __restrict__ v1acc, const float* __restrict__ b1,
    const float* __restrict__ w2, const float* __restrict__ b2,
    float* __restrict__ out)
{
    __shared__ float red[1024];
    int tid = threadIdx.x;
    int j = tid & 127, c = tid >> 7;              // 8 chunks x 128 outputs
    int i0 = c * 57;
    int i1 = i0 + 57; if (i1 > HIDn) i1 = HIDn;
    float acc = 0.f;
    for (int i = i0; i < i1; ++i) {
        float a = fmaxf(v1acc[i] + b1[i], 0.f);
        acc += a * w2[i * FINALn + j];
    }
    red[tid] = acc;
    __syncthreads();
    if (tid < FINALn) {
        float s = 0.f;
        #pragma unroll
        for (int c2 = 0; c2 < 8; ++c2) s += red[c2 * FINALn + tid];
        out[tid] = fmaxf(s + b2[tid], 0.f);
    }
}

extern "C" void kernel_launch(void* const* d_in, const int* in_sizes, int n_in,
                              void* d_out, int out_size, void* d_ws, size_t ws_size,
                              hipStream_t stream)
{
    const float* x      = (const float*)d_in[0];
    const int*   ei     = (const int*)  d_in[1];
    const float* ea     = (const float*)d_in[2];
    const float* mw1    = (const float*)d_in[3];
    const float* mb1    = (const float*)d_in[4];
    const float* mw2    = (const float*)d_in[5];
    const float* mb2    = (const float*)d_in[6];
    const float* nnroot = (const float*)d_in[7];
    const float* nnbias = (const float*)d_in[8];
    const float* gw     = (const float*)d_in[9];
    const float* atts   = (const float*)d_in[10];
    const float* attd   = (const float*)d_in[11];
    const float* gbias  = (const float*)d_in[12];
    const float* f1w    = (const float*)d_in[13];
    const float* f1b    = (const float*)d_in[14];
    const float* f2w    = (const float*)d_in[15];
    const float* f2b    = (const float*)d_in[16];
    float* out = (float*)d_out;

    char* ws = (char*)d_ws;
    size_t p = 0;
    auto alloc = [&](size_t bytes) -> char* {
        char* r = ws + p;
        p += (bytes + 255) & ~(size_t)255;
        return r;
    };
    float* msgbuf = (float*)alloc((size_t)Ee * 64 * 4);   // 81.92 MB
    int*   deg    = (int*)  alloc(Nn * 4 + HIDn * 4);     // deg + v1acc contiguous (one memset)
    float* v1acc  = (float*)(deg + Nn);
    int*   off    = (int*)  alloc((Nn + 1) * 4);
    int*   cursor = (int*)  alloc(Nn * 4);
    int*   srcS   = (int*)  alloc(Ee * 4);
    int*   eidS   = (int*)  alloc(Ee * 4);
    float* xl     = (float*)alloc(Nn * CC * 4);
    float* asrcA  = (float*)alloc(Nn * 4);
    float* adstA  = (float*)alloc(Nn * 4);
    float* x2f    = (float*)alloc(Nn * CC * 4);

    hipMemsetAsync(deg, 0, Nn * 4 + HIDn * 4, stream);

    k_deg    <<<(Ee + 255) / 256, 256, 0, stream>>>(ei, deg);
    k_scan   <<<1, 1024, 0, stream>>>(deg, off, cursor);
    k_scatter<<<(Ee + 255) / 256, 256, 0, stream>>>(ei, cursor, srcS, eidS);
    k_msg    <<<Ee / 256, 256, 0, stream>>>(x, ea, mw1, mb1, mw2, mb2, srcS, eidS, msgbuf);
    k_nodeagg<<<(Nn + 3) / 4, 256, 0, stream>>>(msgbuf, off, x, nnroot, nnbias, gw, atts, attd,
                                                xl, asrcA, adstA);
    k_gat    <<<(Nn + 3) / 4, 256, 0, stream>>>(off, srcS, xl, asrcA, adstA, gbias, x2f);
    k_fc1    <<<(TOT + FC1_ROWS - 1) / FC1_ROWS, 512, 0, stream>>>(x2f, f1w, v1acc);
    k_fc2    <<<1, 1024, 0, stream>>>(v1acc, f1b, f2w, f2b, out);
}

// Round 2
// 788.300 us; speedup vs baseline: 1.1637x; 1.1637x over previous
//
#include <hip/hip_runtime.h>

#define Nn 10000
#define Ee 320000
#define CC 27
#define NEG 0.2f
#define TOT 270000      // Nn*CC
#define HIDn 450
#define FINALn 128
#define FC1_ROWS 264

__device__ __forceinline__ float lrelu(float v) { return v >= 0.f ? v : NEG * v; }

// ---------------- CSR build ----------------
__global__ void k_deg(const int* __restrict__ ei, int* __restrict__ deg) {
    int e = blockIdx.x * blockDim.x + threadIdx.x;
    if (e < Ee) atomicAdd(&deg[ei[Ee + e]], 1);
}

__global__ __launch_bounds__(1024) void k_scan(const int* __restrict__ deg,
                                               int* __restrict__ off,
                                               int* __restrict__ cursor) {
    __shared__ int sums[1024];
    int tid = threadIdx.x;
    const int CH = 10;                       // 1024*10 >= Nn
    int start = tid * CH;
    int local[CH];
    int s = 0;
    #pragma unroll
    for (int i = 0; i < CH; ++i) {
        int idx = start + i;
        int v = (idx < Nn) ? deg[idx] : 0;
        local[i] = v; s += v;
    }
    sums[tid] = s;
    __syncthreads();
    for (int d = 1; d < 1024; d <<= 1) {
        int v = (tid >= d) ? sums[tid - d] : 0;
        __syncthreads();
        sums[tid] += v;
        __syncthreads();
    }
    int run = sums[tid] - s;                 // exclusive prefix
    #pragma unroll
    for (int i = 0; i < CH; ++i) {
        int idx = start + i;
        if (idx < Nn) { off[idx] = run; cursor[idx] = run; run += local[i]; }
    }
    if (tid == 1023) off[Nn] = sums[1023];
}

// pack per-edge record: {src (bits), ea.x, ea.y, 0} so k_agg/k_gat stream one array
__global__ void k_scatter(const int* __restrict__ ei, const float* __restrict__ ea,
                          int* __restrict__ cursor, float4* __restrict__ rec) {
    int e = blockIdx.x * blockDim.x + threadIdx.x;
    if (e < Ee) {
        int d = ei[Ee + e];
        int p = atomicAdd(&cursor[d], 1);
        float2 v = *(const float2*)(ea + 2 * (size_t)e);
        rec[p] = make_float4(__int_as_float(ei[e]), v.x, v.y, 0.f);
    }
}

// ---------------- fused NNConv-aggregate + root + relu + GAT projection ----------------
// One wave per node. Lane k=lane&31 accumulates S[k][i] = sum_edges h_ek * x[src,i]
// (halves of the wave take alternating edges), then per-node projection
// agg[o] = sum_{k,i} S[k][i]*W2[k,i*64+o] + sum_i T[i]*B2[i*64+o]  with o = lane.
__global__ __launch_bounds__(256) void k_agg(
    const float4* __restrict__ rec, const int* __restrict__ off,
    const float* __restrict__ x,
    const float* __restrict__ W1, const float* __restrict__ B1,
    const float* __restrict__ W2, const float* __restrict__ B2,
    const float* __restrict__ nnroot, const float* __restrict__ nnbias,
    const float* __restrict__ gw, const float* __restrict__ attsrc,
    const float* __restrict__ attdst,
    float* __restrict__ xl, float* __restrict__ asrcA, float* __restrict__ adstA)
{
    int wave = threadIdx.x >> 6;
    int lane = threadIdx.x & 63;
    int n = blockIdx.x * 4 + wave;
    if (n >= Nn) return;
    int k = lane & 31, half = lane >> 5;
    float w1a = W1[k], w1b = W1[32 + k], b1k = B1[k];
    int beg = off[n], end = off[n + 1];

    float S0=0,S1=0,S2=0,S3=0,S4=0, T0=0,T1=0,T2=0,T3=0,T4=0;
    for (int j = beg + half; j < end; j += 2) {
        float4 r = rec[j];
        int s = __float_as_int(r.x);
        float h = fmaxf(r.y * w1a + r.z * w1b + b1k, 0.f);
        const float* xp = x + 5 * (size_t)s;
        float x0 = xp[0], x1 = xp[1], x2 = xp[2], x3 = xp[3], x4 = xp[4];
        S0 += h * x0; S1 += h * x1; S2 += h * x2; S3 += h * x3; S4 += h * x4;
        T0 += x0; T1 += x1; T2 += x2; T3 += x3; T4 += x4;
    }
    // combine the two half-wave partial sums
    S0 += __shfl_xor(S0, 32); S1 += __shfl_xor(S1, 32); S2 += __shfl_xor(S2, 32);
    S3 += __shfl_xor(S3, 32); S4 += __shfl_xor(S4, 32);
    T0 += __shfl_xor(T0, 32); T1 += __shfl_xor(T1, 32); T2 += __shfl_xor(T2, 32);
    T3 += __shfl_xor(T3, 32); T4 += __shfl_xor(T4, 32);

    // per-node projection: 160x64 matvec, o = lane (coalesced, L1-hot W2)
    float agg = 0.f;
    #pragma unroll
    for (int kk = 0; kk < 32; ++kk) {
        float s0 = __shfl(S0, kk), s1 = __shfl(S1, kk), s2 = __shfl(S2, kk);
        float s3 = __shfl(S3, kk), s4 = __shfl(S4, kk);
        const float* w = W2 + kk * 320;
        agg += s0*w[lane] + s1*w[64+lane] + s2*w[128+lane] + s3*w[192+lane] + s4*w[256+lane];
    }
    agg += T0*B2[lane] + T1*B2[64+lane] + T2*B2[128+lane] + T3*B2[192+lane] + T4*B2[256+lane];

    // root weight + bias + relu
    const float* xn = x + 5 * (size_t)n;
    float xn0 = xn[0], xn1 = xn[1], xn2 = xn[2], xn3 = xn[3], xn4 = xn[4];
    float v = agg + nnbias[lane]
            + xn0*nnroot[lane] + xn1*nnroot[64+lane] + xn2*nnroot[128+lane]
            + xn3*nnroot[192+lane] + xn4*nnroot[256+lane];
    float x1v = fmaxf(v, 0.f);

    // GAT projection xl[n,c] = sum_o x1[o]*gw[o*27+c]
    int c = (lane < CC) ? lane : 0;
    float xlc = 0.f;
    #pragma unroll
    for (int o = 0; o < 64; ++o) {
        float xo = __shfl(x1v, o);
        xlc += xo * gw[o * CC + c];
    }
    float as_ = (lane < CC) ? xlc * attsrc[c] : 0.f;
    float ad_ = (lane < CC) ? xlc * attdst[c] : 0.f;
    #pragma unroll
    for (int d = 1; d < 64; d <<= 1) {
        as_ += __shfl_xor(as_, d);
        ad_ += __shfl_xor(ad_, d);
    }
    if (lane < CC) xl[n * CC + lane] = xlc;
    if (lane == 0) { asrcA[n] = as_; adstA[n] = ad_; }
}

// ---------------- GAT softmax-aggregate (wave per node, half-wave edge split) ----
__global__ __launch_bounds__(256) void k_gat(
    const int* __restrict__ off, const float4* __restrict__ rec,
    const float* __restrict__ xl, const float* __restrict__ asrcA,
    const float* __restrict__ adstA, const float* __restrict__ gbias,
    float* __restrict__ x2f)
{
    int wave = threadIdx.x >> 6;
    int lane = threadIdx.x & 63;
    int n = blockIdx.x * 4 + wave;
    if (n >= Nn) return;
    int beg = off[n], end = off[n + 1];

    float adn = adstA[n];
    float aself = lrelu(asrcA[n] + adn);

    float m = aself;
    for (int j = beg + lane; j < end; j += 64) {
        int s = __float_as_int(rec[j].x);
        m = fmaxf(m, lrelu(asrcA[s] + adn));
    }
    #pragma unroll
    for (int d = 1; d < 64; d <<= 1) m = fmaxf(m, __shfl_xor(m, d));

    int half = lane >> 5;
    int c = lane & 31; int cc = (c < CC) ? c : 0;
    float denom = 0.f, acc = 0.f;
    for (int j = beg + half; j < end; j += 2) {
        int s = __float_as_int(rec[j].x);
        float w = __expf(lrelu(asrcA[s] + adn) - m);
        denom += w;
        acc += w * xl[s * CC + cc];
    }
    denom += __shfl_xor(denom, 32);
    acc   += __shfl_xor(acc, 32);
    float wself = __expf(aself - m);
    denom += wself;
    acc   += wself * xl[n * CC + cc];

    if (lane < CC) {
        float r = acc / denom + gbias[lane];
        x2f[n * CC + lane] = fmaxf(r, 0.f);
    }
}

// ---------------- fc1: 486MB matvec, skip zero rows ----------------
__global__ __launch_bounds__(512) void k_fc1(
    const float* __restrict__ x2f, const float* __restrict__ fw,
    float* __restrict__ v1acc)
{
    int j = threadIdx.x;
    int t0 = blockIdx.x * FC1_ROWS;
    int t1 = t0 + FC1_ROWS; if (t1 > TOT) t1 = TOT;
    if (j >= HIDn) return;
    float acc = 0.f;
    for (int t = t0; t < t1; t += 4) {
        float4 sv = *(const float4*)(x2f + t);   // block-uniform broadcast
        if (sv.x != 0.f) acc += sv.x * fw[(size_t)t       * HIDn + j];
        if (sv.y != 0.f) acc += sv.y * fw[(size_t)(t + 1) * HIDn + j];
        if (sv.z != 0.f) acc += sv.z * fw[(size_t)(t + 2) * HIDn + j];
        if (sv.w != 0.f) acc += sv.w * fw[(size_t)(t + 3) * HIDn + j];
    }
    atomicAdd(&v1acc[j], acc);
}

// ---------------- fc2 + final relu (single block, split i-dim for ILP) -------------
__global__ __launch_bounds__(1024) void k_fc2(
    const float* __restrict__ v1acc, const float* __restrict__ b1,
    const float* __restrict__ w2, const float* __restrict__ b2,
    float* __restrict__ out)
{
    __shared__ float red[1024];
    int tid = threadIdx.x;
    int j = tid & 127, c = tid >> 7;              // 8 chunks x 128 outputs
    int i0 = c * 57;
    int i1 = i0 + 57; if (i1 > HIDn) i1 = HIDn;
    float acc = 0.f;
    for (int i = i0; i < i1; ++i) {
        float a = fmaxf(v1acc[i] + b1[i], 0.f);
        acc += a * w2[i * FINALn + j];
    }
    red[tid] = acc;
    __syncthreads();
    if (tid < FINALn) {
        float s = 0.f;
        #pragma unroll
        for (int c2 = 0; c2 < 8; ++c2) s += red[c2 * FINALn + tid];
        out[tid] = fmaxf(s + b2[tid], 0.f);
    }
}

extern "C" void kernel_launch(void* const* d_in, const int* in_sizes, int n_in,
                              void* d_out, int out_size, void* d_ws, size_t ws_size,
                              hipStream_t stream)
{
    const float* x      = (const float*)d_in[0];
    const int*   ei     = (const int*)  d_in[1];
    const float* ea     = (const float*)d_in[2];
    const float* mw1    = (const float*)d_in[3];
    const float* mb1    = (const float*)d_in[4];
    const float* mw2    = (const float*)d_in[5];
    const float* mb2    = (const float*)d_in[6];
    const float* nnroot = (const float*)d_in[7];
    const float* nnbias = (const float*)d_in[8];
    const float* gw     = (const float*)d_in[9];
    const float* atts   = (const float*)d_in[10];
    const float* attd   = (const float*)d_in[11];
    const float* gbias  = (const float*)d_in[12];
    const float* f1w    = (const float*)d_in[13];
    const float* f1b    = (const float*)d_in[14];
    const float* f2w    = (const float*)d_in[15];
    const float* f2b    = (const float*)d_in[16];
    float* out = (float*)d_out;

    char* ws = (char*)d_ws;
    size_t p = 0;
    auto alloc = [&](size_t bytes) -> char* {
        char* r = ws + p;
        p += (bytes + 255) & ~(size_t)255;
        return r;
    };
    float4* rec   = (float4*)alloc((size_t)Ee * 16);      // 5.12 MB
    int*    deg   = (int*)   alloc(Nn * 4 + HIDn * 4);    // deg + v1acc (one memset)
    float*  v1acc = (float*)(deg + Nn);
    int*    off   = (int*)   alloc((Nn + 1) * 4);
    int*    cursor= (int*)   alloc(Nn * 4);
    float*  xl    = (float*) alloc(Nn * CC * 4);
    float*  asrcA = (float*) alloc(Nn * 4);
    float*  adstA = (float*) alloc(Nn * 4);
    float*  x2f   = (float*) alloc(TOT * 4);

    hipMemsetAsync(deg, 0, Nn * 4 + HIDn * 4, stream);

    k_deg    <<<(Ee + 255) / 256, 256, 0, stream>>>(ei, deg);
    k_scan   <<<1, 1024, 0, stream>>>(deg, off, cursor);
    k_scatter<<<(Ee + 255) / 256, 256, 0, stream>>>(ei, ea, cursor, rec);
    k_agg    <<<(Nn + 3) / 4, 256, 0, stream>>>(rec, off, x, mw1, mb1, mw2, mb2,
                                                nnroot, nnbias, gw, atts, attd,
                                                xl, asrcA, adstA);
    k_gat    <<<(Nn + 3) / 4, 256, 0, stream>>>(off, rec, xl, asrcA, adstA, gbias, x2f);
    k_fc1    <<<(TOT + FC1_ROWS - 1) / FC1_ROWS, 512, 0, stream>>>(x2f, f1w, v1acc);
    k_fc2    <<<1, 1024, 0, stream>>>(v1acc, f1b, f2w, f2b, out);
}